// Round 13
// baseline (160.231 us; speedup 1.0000x reference)
//
#include <hip/hip_runtime.h>
#include <hip/hip_bf16.h>
#include <math.h>

#define B_  128
#define T_  400
#define E_  128
#define H2_ 256
#define H4_ 512
#define V_  50000
#define G4_ 1024   // 4*H2
#define KACT 384   // E + H2

// output offsets (floats)
#define OFF_H       6400000
#define OFF_C       6432768
#define OFF_ATTN    6465536
#define OFF_COPY    6516736
#define OFF_NEWCOV 12916736
#define OFF_COVLOSS 12967936

// workspace offsets (floats)
#define WS_ACT   0                      // [384][128] act (emb;h0) [k][b]
#define WS_GATES (WS_ACT + KACT*B_)     // [1024][128] gates [j][b]
#define WS_HC    (WS_GATES + G4_*B_)    // [512][128]  (h;ctx) [k][b]
#define WS_FCB   (WS_HC + H4_*B_)       // [128][512]  fc bf16 [b][k]
#define WS_SC    (WS_FCB + H4_*B_/2)    // [128][400]  scores
#define WS_ATTN  (WS_SC + B_*T_)        // [128][400]  attn
#define WS_CTXP  (WS_ATTN + B_*T_)      // [128][8][256] context partials
#define WS_SMP   (WS_CTXP + B_*8*H2_)   // [128][8][2] softmax partials
#define WS_HDOT  (WS_SMP + B_*8*2)      // [128]
#define WS_COVP  (WS_HDOT + B_)         // [128]
#define WS_PGEN  (WS_COVP + B_)         // [128]
#define WS_MAX   (WS_PGEN + B_)         // [128]
#define WS_INV   (WS_MAX + B_)          // [128]
#define WS_AB    (WS_INV + B_)          // [2] alpha, beta

typedef __attribute__((ext_vector_type(8))) short bf16x8;
typedef __attribute__((ext_vector_type(4))) float f32x4;
typedef __attribute__((ext_vector_type(16))) float f32x16;

__device__ inline float sigmoidf_(float x){ return 1.f/(1.f+__expf(-x)); }

__device__ inline short f2bf(float x){
  __hip_bfloat16 h = __float2bfloat16(x);
  return *reinterpret_cast<short*>(&h);
}

__device__ __forceinline__ void load_to_lds16(const void* g, void* l){
  __builtin_amdgcn_global_load_lds(
      (const __attribute__((address_space(1))) void*)g,
      (__attribute__((address_space(3))) void*)l, 16, 0, 0);
}

__device__ inline float blk_reduce_sum(float v, float* red){
  int t = threadIdx.x;
  red[t] = v; __syncthreads();
  for (int s = 128; s > 0; s >>= 1){ if (t < s) red[t] += red[t+s]; __syncthreads(); }
  float r = red[0]; __syncthreads(); return r;
}
__device__ inline float blk_reduce_max(float v, float* red){
  int t = threadIdx.x;
  red[t] = v; __syncthreads();
  for (int s = 128; s > 0; s >>= 1){ if (t < s) red[t] = fmaxf(red[t], red[t+s]); __syncthreads(); }
  float r = red[0]; __syncthreads(); return r;
}

// ---- K_zero: fast zero of o_copy ----
__global__ __launch_bounds__(256) void k_zero(float* __restrict__ p){
  size_t i = ((size_t)blockIdx.x*256 + threadIdx.x)*4;
  if (i < (size_t)B_*V_)
    *(float4*)&p[i] = make_float4(0.f,0.f,0.f,0.f);
}

// ---- K0: act[k][b] = concat(emb,h0) transposed; block 0 also computes alpha/beta ----
__global__ __launch_bounds__(256) void k_act(const int* __restrict__ ids,
    const float* __restrict__ pre_h, const float* __restrict__ emb_table,
    const float* __restrict__ w_align, const float* __restrict__ w_cov,
    const float* __restrict__ b_cov, float* __restrict__ act,
    float* __restrict__ ab){
  __shared__ float red[256];
  int t = threadIdx.x;
  int idx = blockIdx.x*256 + t;
  int k = idx >> 7, b = idx & 127;
  float v = (k < E_) ? emb_table[(size_t)ids[b]*E_ + k]
                     : pre_h[b*H2_ + (k - E_)];
  act[idx] = v;
  if (blockIdx.x == 0) {
    float wa = w_align[2*H2_ + t];
    float alpha = blk_reduce_sum(w_cov[t]*wa, red);
    float beta  = blk_reduce_sum(b_cov[t]*wa, red);
    if (t == 0) { ab[0] = alpha; ab[1] = beta; }
  }
}

// ---- K1: gates[j][b] ----
__global__ __launch_bounds__(256) void k_gates(const float* __restrict__ act,
    const float* __restrict__ w_ih, const float* __restrict__ w_hh,
    const float* __restrict__ b_ih, const float* __restrict__ b_hh,
    float* __restrict__ gates){
  __shared__ float wt[8][KACT];
  int t = threadIdx.x; int j0 = blockIdx.x*8;
  for (int idx = t; idx < 8*KACT; idx += 256) {
    int r = idx / KACT, k = idx % KACT;
    int j = j0 + r;
    wt[r][k] = (k < E_) ? w_ih[j*E_ + k] : w_hh[j*H2_ + (k - E_)];
  }
  __syncthreads();
  int jq = t >> 7, b = t & 127;
  float acc[4] = {0.f,0.f,0.f,0.f};
  for (int k = 0; k < KACT; ++k) {
    float a = act[k*B_ + b];
    #pragma unroll
    for (int jj = 0; jj < 4; ++jj) acc[jj] += wt[jq*4+jj][k]*a;
  }
  #pragma unroll
  for (int jj = 0; jj < 4; ++jj) {
    int j = j0 + jq*4 + jj;
    gates[j*B_ + b] = acc[jj] + b_ih[j] + b_hh[j];
  }
}

// ---- K2: LSTM elementwise + hdot ----
__global__ __launch_bounds__(256) void k_lstm(const float* __restrict__ gates,
    const float* __restrict__ pre_c, const float* __restrict__ w_align,
    float* __restrict__ o_h, float* __restrict__ o_c,
    float* __restrict__ hc, float* __restrict__ hdot){
  __shared__ float red[256];
  int b = blockIdx.x, k = threadIdx.x;
  float i_ = gates[(0*H2_ + k)*B_ + b];
  float f_ = gates[(1*H2_ + k)*B_ + b];
  float g_ = gates[(2*H2_ + k)*B_ + b];
  float o_ = gates[(3*H2_ + k)*B_ + b];
  float c = sigmoidf_(f_)*pre_c[b*H2_ + k] + sigmoidf_(i_)*tanhf(g_);
  float h = sigmoidf_(o_)*tanhf(c);
  o_h[b*H2_ + k] = h;
  o_c[b*H2_ + k] = c;
  hc[k*B_ + b] = h;
  float s = blk_reduce_sum(h * w_align[H2_ + k], red);
  if (k == 0) hdot[b] = s;
}

// ---- K3a: scores, grid (8 chunks of 50, B) ----
__global__ __launch_bounds__(256) void k_scores(const float* __restrict__ enc,
    const float* __restrict__ cov, const float* __restrict__ w_align,
    const float* __restrict__ b_align, const float* __restrict__ hdot,
    const float* __restrict__ ab, float* __restrict__ sc){
  int b = blockIdx.y, c = blockIdx.x;
  int t = threadIdx.x, wave = t >> 6, lane = t & 63;
  float4 wa4 = *(const float4*)&w_align[lane*4];
  float hd = hdot[b], alpha = ab[0], beta = ab[1], ba = b_align[0];
  int t0 = c*50;
  for (int tt = t0 + wave; tt < t0 + 50; tt += 4) {
    const float4* ep = (const float4*)&enc[((size_t)b*T_ + tt)*H2_];
    float4 e4 = ep[lane];
    float d = e4.x*wa4.x + e4.y*wa4.y + e4.z*wa4.z + e4.w*wa4.w;
    #pragma unroll
    for (int m = 32; m >= 1; m >>= 1) d += __shfl_xor(d, m);
    if (lane == 0)
      sc[b*T_ + tt] = tanhf(d + hd + alpha*cov[b*T_ + tt] + beta + ba);
  }
}

// ---- K3b: softmax over T + scatter + newcov + covloss partial ----
__global__ __launch_bounds__(256) void k_soft(const float* __restrict__ sc_in,
    const float* __restrict__ cov, const int* __restrict__ src,
    float* __restrict__ o_attn, float* __restrict__ o_newcov,
    float* __restrict__ o_copy, float* __restrict__ covp,
    float* __restrict__ attn_ws){
  __shared__ float red[256];
  int b = blockIdx.x, t = threadIdx.x;
  float x1 = sc_in[b*T_ + t];
  float x2 = (t + 256 < T_) ? sc_in[b*T_ + t + 256] : -1e30f;
  float mx = blk_reduce_max(fmaxf(x1, x2), red);
  float e1 = __expf(x1 - mx);
  float e2 = (t + 256 < T_) ? __expf(x2 - mx) : 0.f;
  float sum = blk_reduce_sum(e1 + e2, red);
  float inv = 1.f/sum;
  float cl;
  {
    float a1 = e1*inv; float c1 = cov[b*T_ + t];
    attn_ws[b*T_ + t] = a1;
    o_attn[b*T_ + t] = a1;
    o_newcov[b*T_ + t] = c1 + a1;
    atomicAdd(&o_copy[(size_t)b*V_ + src[b*T_ + t]], a1);
    cl = fminf(a1, c1);
  }
  if (t + 256 < T_) {
    float a2 = e2*inv; float c2 = cov[b*T_ + t + 256];
    attn_ws[b*T_ + t + 256] = a2;
    o_attn[b*T_ + t + 256] = a2;
    o_newcov[b*T_ + t + 256] = c2 + a2;
    atomicAdd(&o_copy[(size_t)b*V_ + src[b*T_ + t + 256]], a2);
    cl += fminf(a2, c2);
  }
  float clsum = blk_reduce_sum(cl, red);
  if (t == 0) covp[b] = clsum;
}

// ---- K3c: context partials, grid (8 chunks, B) ----
__global__ __launch_bounds__(256) void k_ctx(const float* __restrict__ enc,
    const float* __restrict__ attn_ws, float* __restrict__ ctxp){
  __shared__ float a_s[50];
  int b = blockIdx.y, c = blockIdx.x, e = threadIdx.x;
  int t0 = c*50;
  if (e < 50) a_s[e] = attn_ws[b*T_ + t0 + e];
  __syncthreads();
  float acc = 0.f;
  #pragma unroll 5
  for (int i = 0; i < 50; ++i)
    acc += a_s[i] * enc[((size_t)b*T_ + t0 + i)*H2_ + e];
  ctxp[((size_t)b*8 + c)*H2_ + e] = acc;
}

// ---- K3d: context reduce + pgen ----
__global__ __launch_bounds__(256) void k_ctxpgen(const float* __restrict__ ctxp,
    const int* __restrict__ ids, const float* __restrict__ emb_table,
    const float* __restrict__ w_gen, const float* __restrict__ b_gen,
    float* __restrict__ hc, float* __restrict__ pgen){
  __shared__ float red[256];
  int b = blockIdx.x, t = threadIdx.x;
  float ctx = 0.f;
  #pragma unroll
  for (int c = 0; c < 8; ++c) ctx += ctxp[((size_t)b*8 + c)*H2_ + t];
  hc[(H2_ + t)*B_ + b] = ctx;
  float p = ctx*w_gen[t] + hc[t*B_ + b]*w_gen[H2_ + t];
  if (t < E_) p += emb_table[(size_t)ids[b]*E_ + t]*w_gen[2*H2_ + t];
  float s = blk_reduce_sum(p, red);
  if (t == 0) pgen[b] = sigmoidf_(s + b_gen[0]);
}

// ---- K4: fc1, output bf16 [b][k] ----
__global__ __launch_bounds__(256) void k_fc1(const float* __restrict__ hc,
    const float* __restrict__ w_fc1, const float* __restrict__ b_fc1,
    short* __restrict__ fcb){
  __shared__ float wt[16][H4_];
  int t = threadIdx.x; int j0 = blockIdx.x*16;
  for (int idx = t; idx < 16*H4_; idx += 256) {
    int r = idx >> 9, k = idx & 511;
    wt[r][k] = w_fc1[(j0 + r)*H4_ + k];
  }
  __syncthreads();
  int jq = t >> 7, b = t & 127;
  float acc[8] = {};
  for (int k = 0; k < H4_; ++k) {
    float a = hc[k*B_ + b];
    #pragma unroll
    for (int jj = 0; jj < 8; ++jj) acc[jj] += wt[jq*8+jj][k]*a;
  }
  bf16x8 pack;
  #pragma unroll
  for (int jj = 0; jj < 8; ++jj) {
    int j = j0 + jq*8 + jj;
    pack[jj] = f2bf(tanhf(acc[jj] + b_fc1[j]));
  }
  *(bf16x8*)&fcb[(size_t)b*H4_ + j0 + jq*8] = pack;
}

// ---- K5: MFMA 32x32x16 GEMM via global_load_lds + counted-vmcnt pipeline.
// logits[b][v] = fcb[b][:]·w_fc2[v][:] + b_fc2[v]
// 16 chunks of 32 k. 3 LDS buffers (A 8KB + W 16KB each = 72KB). Loads go
// DIRECT to LDS (no VGPR staging, no ds_write): before computing chunk c we
// wait only vmcnt(12) — the 12 younger gload_lds for c+1/c+2 stay in flight
// across the raw s_barrier (never vmcnt(0) in the loop; T3+T4). Swizzled LDS
// layout achieved by pre-swizzling each lane's GLOBAL source address (m173),
// LDS dest stays linear (wave-uniform base + lane*16). sched_barrier(0)
// after each wait fences ds_read hoisting (rule 18).
__global__ __launch_bounds__(256, 2) void k_gemm2m(const short* __restrict__ fcb,
    const float* __restrict__ w_fc2, const float* __restrict__ b_fc2,
    float* __restrict__ logits){
  __shared__ __attribute__((aligned(16))) char lds[73728];   // 3 x 24KB
  int t = threadIdx.x;
  int w = t >> 6, l = t & 63;
  int ln = l & 31, g2 = l >> 5;
  int v0 = blockIdx.x*128;
  int v = v0 + w*32 + ln;
  int vl = w*32 + ln;
  (void)vl;

  // 6 gload_lds slots per wave per chunk: 1536 16B-slots (A 512 + W 1024),
  // slot g = (w*6+j)*64 + l. Per-lane swizzled global source; uniform LDS base.
  const char* gsrc[6];
  int cstride[6];
  int lbase = w*6*1024;
  #pragma unroll
  for (int j = 0; j < 6; ++j) {
    int g = (w*6 + j)*64 + l;
    if (g < 512) {          // A slot: q=k-subgroup(16B), r=row; s = q*128 + (r^(q<<1))
      int q = g >> 7, r = (g & 127) ^ ((q << 1) & 127);
      gsrc[j] = (const char*)(fcb + r*H4_ + q*8);
      cstride[j] = 64;      // 32 shorts per chunk
    } else {                // W slot: kg=k-subgroup(16B), row=v; s = kg*128 + (row^kg)
      int s = g - 512;
      int kg = s >> 7, row = (s & 127) ^ kg;
      int vr = v0 + row; if (vr >= V_) vr = V_ - 1;
      gsrc[j] = (const char*)(w_fc2 + (size_t)vr*H4_ + kg*4);
      cstride[j] = 128;     // 32 floats per chunk
    }
  }

  f32x16 acc0 = {}, acc1 = {}, acc2 = {}, acc3 = {};

  #define ISSUE(c, bi) {                                                      \
    char* bb = lds + (bi)*24576;                                              \
    _Pragma("unroll")                                                         \
    for (int j = 0; j < 6; ++j)                                               \
      load_to_lds16(gsrc[j] + (c)*cstride[j], bb + lbase + j*1024);           \
    __builtin_amdgcn_sched_barrier(0);                                        \
  }
  #define COMPUTE(c) {                                                        \
    char* Ab = lds + ((c) % 3)*24576;                                         \
    char* Wb = Ab + 8192;                                                     \
    _Pragma("unroll")                                                         \
    for (int s = 0; s < 2; ++s) {                                             \
      int sg = s*2 + g2;                                                      \
      bf16x8 a0 = *(const bf16x8*)(Ab + sg*2048 + ((( 0+ln) ^ (sg<<1)) & 127)*16); \
      bf16x8 a1 = *(const bf16x8*)(Ab + sg*2048 + (((32+ln) ^ (sg<<1)) & 127)*16); \
      bf16x8 a2 = *(const bf16x8*)(Ab + sg*2048 + (((64+ln) ^ (sg<<1)) & 127)*16); \
      bf16x8 a3 = *(const bf16x8*)(Ab + sg*2048 + (((96+ln) ^ (sg<<1)) & 127)*16); \
      int kgA = s*4 + g2*2;                                                   \
      f32x4 f0 = *(const f32x4*)(Wb + kgA*2048 + (((w*32+ln) ^ kgA) & 127)*16); \
      int kgB = kgA + 1;                                                      \
      f32x4 f1 = *(const f32x4*)(Wb + kgB*2048 + (((w*32+ln) ^ kgB) & 127)*16); \
      bf16x8 bf;                                                              \
      bf[0]=f2bf(f0[0]); bf[1]=f2bf(f0[1]); bf[2]=f2bf(f0[2]); bf[3]=f2bf(f0[3]); \
      bf[4]=f2bf(f1[0]); bf[5]=f2bf(f1[1]); bf[6]=f2bf(f1[2]); bf[7]=f2bf(f1[3]); \
      acc0 = __builtin_amdgcn_mfma_f32_32x32x16_bf16(a0, bf, acc0, 0, 0, 0);  \
      acc1 = __builtin_amdgcn_mfma_f32_32x32x16_bf16(a1, bf, acc1, 0, 0, 0);  \
      acc2 = __builtin_amdgcn_mfma_f32_32x32x16_bf16(a2, bf, acc2, 0, 0, 0);  \
      acc3 = __builtin_amdgcn_mfma_f32_32x32x16_bf16(a3, bf, acc3, 0, 0, 0);  \
    }                                                                         \
  }
  #define STEP(c, n) {                                                        \
    asm volatile("s_waitcnt vmcnt(" #n ")" ::: "memory");                     \
    __builtin_amdgcn_s_barrier();                                             \
    __builtin_amdgcn_sched_barrier(0);                                        \
    COMPUTE(c)                                                                \
    asm volatile("s_waitcnt lgkmcnt(0)" ::: "memory");                        \
    __builtin_amdgcn_s_barrier();                                             \
    __builtin_amdgcn_sched_barrier(0);                                        \
    ISSUE((c)+3, (c)%3)                                                       \
  }
  #define STEPE(c, n) {                                                       \
    asm volatile("s_waitcnt vmcnt(" #n ")" ::: "memory");                     \
    __builtin_amdgcn_s_barrier();                                             \
    __builtin_amdgcn_sched_barrier(0);                                        \
    COMPUTE(c)                                                                \
  }

  ISSUE(0, 0) ISSUE(1, 1) ISSUE(2, 2)
  STEP(0, 12)  STEP(1, 12)  STEP(2, 12)  STEP(3, 12)
  STEP(4, 12)  STEP(5, 12)  STEP(6, 12)  STEP(7, 12)
  STEP(8, 12)  STEP(9, 12)  STEP(10, 12) STEP(11, 12)
  STEP(12, 12)
  STEPE(13, 12) STEPE(14, 6) STEPE(15, 0)

  #undef ISSUE
  #undef COMPUTE
  #undef STEP
  #undef STEPE

  if (v < V_) {
    float bias = b_fc2[v];
    #pragma unroll
    for (int r = 0; r < 16; ++r) {
      int brow = (r & 3) + 8*(r >> 2) + 4*g2;
      logits[(size_t)(brow)*V_ + v]      = acc0[r] + bias;
      logits[(size_t)(32 + brow)*V_ + v] = acc1[r] + bias;
      logits[(size_t)(64 + brow)*V_ + v] = acc2[r] + bias;
      logits[(size_t)(96 + brow)*V_ + v] = acc3[r] + bias;
    }
  }
}

// ---- K6a: softmax partial stats, grid (8, B) ----
__global__ __launch_bounds__(256) void k_smp(const float* __restrict__ logits,
    float* __restrict__ smp){
  __shared__ float rm[256], rs[256];
  int b = blockIdx.y, c = blockIdx.x, t = threadIdx.x;
  int v0 = c*6250, v1 = v0 + 6250;
  float m = -1e30f, s = 0.f;
  for (int v = v0 + t; v < v1; v += 256) {
    float x = logits[(size_t)b*V_ + v];
    float nm = fmaxf(m, x);
    s = s*__expf(m - nm) + __expf(x - nm);
    m = nm;
  }
  rm[t] = m; rs[t] = s; __syncthreads();
  for (int k = 128; k > 0; k >>= 1) {
    if (t < k) {
      float m1 = rm[t], s1 = rs[t], m2 = rm[t+k], s2 = rs[t+k];
      float nm = fmaxf(m1, m2);
      rm[t] = nm; rs[t] = s1*__expf(m1-nm) + s2*__expf(m2-nm);
    }
    __syncthreads();
  }
  if (t == 0) { smp[(b*8+c)*2] = rm[0]; smp[(b*8+c)*2+1] = rs[0]; }
}

// ---- K6b: combine stats + covloss ----
__global__ __launch_bounds__(128) void k_smred_cl(const float* __restrict__ smp,
    const float* __restrict__ covp, float* __restrict__ mx,
    float* __restrict__ inv, float* __restrict__ o_cl){
  __shared__ float red[128];
  int t = threadIdx.x;
  float m = -1e30f, s = 0.f;
  #pragma unroll
  for (int c = 0; c < 8; ++c) {
    float m2 = smp[(t*8+c)*2], s2 = smp[(t*8+c)*2+1];
    float nm = fmaxf(m, m2);
    s = s*__expf(m - nm) + s2*__expf(m2 - nm);
    m = nm;
  }
  mx[t] = m; inv[t] = 1.f/s;
  red[t] = covp[t]; __syncthreads();
  for (int k = 64; k > 0; k >>= 1){ if (t < k) red[t] += red[t+k]; __syncthreads(); }
  if (t == 0) o_cl[0] = red[0];
}

// ---- K7: final mix (float4) ----
__global__ __launch_bounds__(256) void k_final(const float* __restrict__ copy,
    const float* __restrict__ mx, const float* __restrict__ inv_s,
    const float* __restrict__ pgen, float* __restrict__ out){
  size_t gid = (size_t)blockIdx.x*256 + threadIdx.x;
  int b = (int)(gid / (V_/4));
  int v = (int)(gid % (V_/4))*4;
  size_t idx = (size_t)b*V_ + v;
  float m = mx[b], is = inv_s[b], pg = pgen[b];
  float4 lg = *(const float4*)&out[idx];
  float4 cp = *(const float4*)&copy[idx];
  float4 o;
  o.x = __expf(lg.x - m)*is*pg + cp.x*(1.f - pg);
  o.y = __expf(lg.y - m)*is*pg + cp.y*(1.f - pg);
  o.z = __expf(lg.z - m)*is*pg + cp.z*(1.f - pg);
  o.w = __expf(lg.w - m)*is*pg + cp.w*(1.f - pg);
  *(float4*)&out[idx] = o;
}

extern "C" void kernel_launch(void* const* d_in, const int* in_sizes, int n_in,
                              void* d_out, int out_size, void* d_ws, size_t ws_size,
                              hipStream_t stream) {
  const int*   ids       = (const int*)  d_in[0];
  const float* pre_h     = (const float*)d_in[1];
  const float* pre_c     = (const float*)d_in[2];
  const float* enc       = (const float*)d_in[3];
  const int*   src       = (const int*)  d_in[4];
  const float* cov       = (const float*)d_in[5];
  const float* emb_table = (const float*)d_in[6];
  const float* w_ih      = (const float*)d_in[7];
  const float* w_hh      = (const float*)d_in[8];
  const float* b_ih      = (const float*)d_in[9];
  const float* b_hh      = (const float*)d_in[10];
  const float* w_align   = (const float*)d_in[11];
  const float* b_align   = (const float*)d_in[12];
  const float* w_cov     = (const float*)d_in[13];
  const float* b_cov     = (const float*)d_in[14];
  const float* w_fc1     = (const float*)d_in[15];
  const float* b_fc1     = (const float*)d_in[16];
  const float* w_fc2     = (const float*)d_in[17];
  const float* b_fc2     = (const float*)d_in[18];
  const float* w_gen     = (const float*)d_in[19];
  const float* b_gen     = (const float*)d_in[20];

  float* out = (float*)d_out;
  float* ws  = (float*)d_ws;

  float* o_out    = out;
  float* o_h      = out + OFF_H;
  float* o_c      = out + OFF_C;
  float* o_attn   = out + OFF_ATTN;
  float* o_copy   = out + OFF_COPY;
  float* o_newcov = out + OFF_NEWCOV;
  float* o_cl     = out + OFF_COVLOSS;

  k_zero <<<(B_*V_/4 + 255)/256, 256, 0, stream>>>(o_copy);
  k_act  <<<192, 256, 0, stream>>>(ids, pre_h, emb_table, w_align, w_cov, b_cov,
                                   ws + WS_ACT, ws + WS_AB);
  k_gates<<<128, 256, 0, stream>>>(ws + WS_ACT, w_ih, w_hh, b_ih, b_hh, ws + WS_GATES);
  k_lstm <<<128, 256, 0, stream>>>(ws + WS_GATES, pre_c, w_align, o_h, o_c,
                                   ws + WS_HC, ws + WS_HDOT);
  k_scores<<<dim3(8,128), 256, 0, stream>>>(enc, cov, w_align, b_align,
                                   ws + WS_HDOT, ws + WS_AB, ws + WS_SC);
  k_soft <<<128, 256, 0, stream>>>(ws + WS_SC, cov, src, o_attn, o_newcov, o_copy,
                                   ws + WS_COVP, ws + WS_ATTN);
  k_ctx  <<<dim3(8,128), 256, 0, stream>>>(enc, ws + WS_ATTN, ws + WS_CTXP);
  k_ctxpgen<<<128, 256, 0, stream>>>(ws + WS_CTXP, ids, emb_table, w_gen, b_gen,
                                   ws + WS_HC, ws + WS_PGEN);
  k_fc1  <<<32, 256, 0, stream>>>(ws + WS_HC, w_fc1, b_fc1, (short*)(ws + WS_FCB));
  k_gemm2m<<<(V_ + 127)/128, 256, 0, stream>>>((const short*)(ws + WS_FCB),
                                   w_fc2, b_fc2, o_out);
  k_smp  <<<dim3(8,128), 256, 0, stream>>>(o_out, ws + WS_SMP);
  k_smred_cl<<<1, 128, 0, stream>>>(ws + WS_SMP, ws + WS_COVP,
                                   ws + WS_MAX, ws + WS_INV, o_cl);
  k_final<<<(int)(((size_t)B_*V_/4)/256), 256, 0, stream>>>(
      o_copy, ws + WS_MAX, ws + WS_INV, ws + WS_PGEN, o_out);
}

// Round 14
// 143.303 us; speedup vs baseline: 1.1181x; 1.1181x over previous
//
#include <hip/hip_runtime.h>
#include <hip/hip_bf16.h>
#include <math.h>

#define B_  128
#define T_  400
#define E_  128
#define H2_ 256
#define H4_ 512
#define V_  50000
#define G4_ 1024   // 4*H2
#define KACT 384   // E + H2

// output offsets (floats)
#define OFF_H       6400000
#define OFF_C       6432768
#define OFF_ATTN    6465536
#define OFF_COPY    6516736
#define OFF_NEWCOV 12916736
#define OFF_COVLOSS 12967936

// workspace offsets (floats)
#define WS_ACT   0                      // [384][128] act (emb;h0) [k][b]
#define WS_GATES (WS_ACT + KACT*B_)     // [1024][128] gates [j][b]
#define WS_HC    (WS_GATES + G4_*B_)    // [512][128]  (h;ctx) [k][b]
#define WS_FCB   (WS_HC + H4_*B_)       // [128][512]  fc bf16 [b][k]
#define WS_SC    (WS_FCB + H4_*B_/2)    // [128][400]  scores
#define WS_ATTN  (WS_SC + B_*T_)        // [128][400]  attn
#define WS_CTXP  (WS_ATTN + B_*T_)      // [128][8][256] context partials
#define WS_SMP   (WS_CTXP + B_*8*H2_)   // [128][8][2] softmax partials
#define WS_HDOT  (WS_SMP + B_*8*2)      // [128]
#define WS_COVP  (WS_HDOT + B_)         // [128]
#define WS_PGEN  (WS_COVP + B_)         // [128]
#define WS_MAX   (WS_PGEN + B_)         // [128]
#define WS_INV   (WS_MAX + B_)          // [128]
#define WS_AB    (WS_INV + B_)          // [2] alpha, beta (+pad)
#define WS_LOGB  (WS_AB + 16)           // [128][50000] bf16 logits (as shorts)

typedef __attribute__((ext_vector_type(8))) short bf16x8;
typedef __attribute__((ext_vector_type(4))) float f32x4;
typedef __attribute__((ext_vector_type(16))) float f32x16;

__device__ inline float sigmoidf_(float x){ return 1.f/(1.f+__expf(-x)); }

__device__ inline short f2bf(float x){
  __hip_bfloat16 h = __float2bfloat16(x);
  return *reinterpret_cast<short*>(&h);
}
__device__ inline float bf2f(unsigned short u){
  unsigned int x = ((unsigned int)u) << 16;
  return *reinterpret_cast<float*>(&x);
}

__device__ inline float blk_reduce_sum(float v, float* red){
  int t = threadIdx.x;
  red[t] = v; __syncthreads();
  for (int s = 128; s > 0; s >>= 1){ if (t < s) red[t] += red[t+s]; __syncthreads(); }
  float r = red[0]; __syncthreads(); return r;
}
__device__ inline float blk_reduce_max(float v, float* red){
  int t = threadIdx.x;
  red[t] = v; __syncthreads();
  for (int s = 128; s > 0; s >>= 1){ if (t < s) red[t] = fmaxf(red[t], red[t+s]); __syncthreads(); }
  float r = red[0]; __syncthreads(); return r;
}

// ---- K_zero: fast zero of o_copy ----
__global__ __launch_bounds__(256) void k_zero(float* __restrict__ p){
  size_t i = ((size_t)blockIdx.x*256 + threadIdx.x)*4;
  if (i < (size_t)B_*V_)
    *(float4*)&p[i] = make_float4(0.f,0.f,0.f,0.f);
}

// ---- K0: act[k][b] = concat(emb,h0) transposed; block 0 also computes alpha/beta ----
__global__ __launch_bounds__(256) void k_act(const int* __restrict__ ids,
    const float* __restrict__ pre_h, const float* __restrict__ emb_table,
    const float* __restrict__ w_align, const float* __restrict__ w_cov,
    const float* __restrict__ b_cov, float* __restrict__ act,
    float* __restrict__ ab){
  __shared__ float red[256];
  int t = threadIdx.x;
  int idx = blockIdx.x*256 + t;
  int k = idx >> 7, b = idx & 127;
  float v = (k < E_) ? emb_table[(size_t)ids[b]*E_ + k]
                     : pre_h[b*H2_ + (k - E_)];
  act[idx] = v;
  if (blockIdx.x == 0) {
    float wa = w_align[2*H2_ + t];
    float alpha = blk_reduce_sum(w_cov[t]*wa, red);
    float beta  = blk_reduce_sum(b_cov[t]*wa, red);
    if (t == 0) { ab[0] = alpha; ab[1] = beta; }
  }
}

// ---- K1: gates[j][b] ----
__global__ __launch_bounds__(256) void k_gates(const float* __restrict__ act,
    const float* __restrict__ w_ih, const float* __restrict__ w_hh,
    const float* __restrict__ b_ih, const float* __restrict__ b_hh,
    float* __restrict__ gates){
  __shared__ float wt[8][KACT];
  int t = threadIdx.x; int j0 = blockIdx.x*8;
  for (int idx = t; idx < 8*KACT; idx += 256) {
    int r = idx / KACT, k = idx % KACT;
    int j = j0 + r;
    wt[r][k] = (k < E_) ? w_ih[j*E_ + k] : w_hh[j*H2_ + (k - E_)];
  }
  __syncthreads();
  int jq = t >> 7, b = t & 127;
  float acc[4] = {0.f,0.f,0.f,0.f};
  for (int k = 0; k < KACT; ++k) {
    float a = act[k*B_ + b];
    #pragma unroll
    for (int jj = 0; jj < 4; ++jj) acc[jj] += wt[jq*4+jj][k]*a;
  }
  #pragma unroll
  for (int jj = 0; jj < 4; ++jj) {
    int j = j0 + jq*4 + jj;
    gates[j*B_ + b] = acc[jj] + b_ih[j] + b_hh[j];
  }
}

// ---- K2: LSTM elementwise + hdot ----
__global__ __launch_bounds__(256) void k_lstm(const float* __restrict__ gates,
    const float* __restrict__ pre_c, const float* __restrict__ w_align,
    float* __restrict__ o_h, float* __restrict__ o_c,
    float* __restrict__ hc, float* __restrict__ hdot){
  __shared__ float red[256];
  int b = blockIdx.x, k = threadIdx.x;
  float i_ = gates[(0*H2_ + k)*B_ + b];
  float f_ = gates[(1*H2_ + k)*B_ + b];
  float g_ = gates[(2*H2_ + k)*B_ + b];
  float o_ = gates[(3*H2_ + k)*B_ + b];
  float c = sigmoidf_(f_)*pre_c[b*H2_ + k] + sigmoidf_(i_)*tanhf(g_);
  float h = sigmoidf_(o_)*tanhf(c);
  o_h[b*H2_ + k] = h;
  o_c[b*H2_ + k] = c;
  hc[k*B_ + b] = h;
  float s = blk_reduce_sum(h * w_align[H2_ + k], red);
  if (k == 0) hdot[b] = s;
}

// ---- K3a: scores, grid (8 chunks of 50, B) ----
__global__ __launch_bounds__(256) void k_scores(const float* __restrict__ enc,
    const float* __restrict__ cov, const float* __restrict__ w_align,
    const float* __restrict__ b_align, const float* __restrict__ hdot,
    const float* __restrict__ ab, float* __restrict__ sc){
  int b = blockIdx.y, c = blockIdx.x;
  int t = threadIdx.x, wave = t >> 6, lane = t & 63;
  float4 wa4 = *(const float4*)&w_align[lane*4];
  float hd = hdot[b], alpha = ab[0], beta = ab[1], ba = b_align[0];
  int t0 = c*50;
  for (int tt = t0 + wave; tt < t0 + 50; tt += 4) {
    const float4* ep = (const float4*)&enc[((size_t)b*T_ + tt)*H2_];
    float4 e4 = ep[lane];
    float d = e4.x*wa4.x + e4.y*wa4.y + e4.z*wa4.z + e4.w*wa4.w;
    #pragma unroll
    for (int m = 32; m >= 1; m >>= 1) d += __shfl_xor(d, m);
    if (lane == 0)
      sc[b*T_ + tt] = tanhf(d + hd + alpha*cov[b*T_ + tt] + beta + ba);
  }
}

// ---- K3b: softmax over T + scatter + newcov + covloss partial ----
__global__ __launch_bounds__(256) void k_soft(const float* __restrict__ sc_in,
    const float* __restrict__ cov, const int* __restrict__ src,
    float* __restrict__ o_attn, float* __restrict__ o_newcov,
    float* __restrict__ o_copy, float* __restrict__ covp,
    float* __restrict__ attn_ws){
  __shared__ float red[256];
  int b = blockIdx.x, t = threadIdx.x;
  float x1 = sc_in[b*T_ + t];
  float x2 = (t + 256 < T_) ? sc_in[b*T_ + t + 256] : -1e30f;
  float mx = blk_reduce_max(fmaxf(x1, x2), red);
  float e1 = __expf(x1 - mx);
  float e2 = (t + 256 < T_) ? __expf(x2 - mx) : 0.f;
  float sum = blk_reduce_sum(e1 + e2, red);
  float inv = 1.f/sum;
  float cl;
  {
    float a1 = e1*inv; float c1 = cov[b*T_ + t];
    attn_ws[b*T_ + t] = a1;
    o_attn[b*T_ + t] = a1;
    o_newcov[b*T_ + t] = c1 + a1;
    atomicAdd(&o_copy[(size_t)b*V_ + src[b*T_ + t]], a1);
    cl = fminf(a1, c1);
  }
  if (t + 256 < T_) {
    float a2 = e2*inv; float c2 = cov[b*T_ + t + 256];
    attn_ws[b*T_ + t + 256] = a2;
    o_attn[b*T_ + t + 256] = a2;
    o_newcov[b*T_ + t + 256] = c2 + a2;
    atomicAdd(&o_copy[(size_t)b*V_ + src[b*T_ + t + 256]], a2);
    cl += fminf(a2, c2);
  }
  float clsum = blk_reduce_sum(cl, red);
  if (t == 0) covp[b] = clsum;
}

// ---- K3c: context partials, grid (8 chunks, B) ----
__global__ __launch_bounds__(256) void k_ctx(const float* __restrict__ enc,
    const float* __restrict__ attn_ws, float* __restrict__ ctxp){
  __shared__ float a_s[50];
  int b = blockIdx.y, c = blockIdx.x, e = threadIdx.x;
  int t0 = c*50;
  if (e < 50) a_s[e] = attn_ws[b*T_ + t0 + e];
  __syncthreads();
  float acc = 0.f;
  #pragma unroll 5
  for (int i = 0; i < 50; ++i)
    acc += a_s[i] * enc[((size_t)b*T_ + t0 + i)*H2_ + e];
  ctxp[((size_t)b*8 + c)*H2_ + e] = acc;
}

// ---- K3d: context reduce + pgen ----
__global__ __launch_bounds__(256) void k_ctxpgen(const float* __restrict__ ctxp,
    const int* __restrict__ ids, const float* __restrict__ emb_table,
    const float* __restrict__ w_gen, const float* __restrict__ b_gen,
    float* __restrict__ hc, float* __restrict__ pgen){
  __shared__ float red[256];
  int b = blockIdx.x, t = threadIdx.x;
  float ctx = 0.f;
  #pragma unroll
  for (int c = 0; c < 8; ++c) ctx += ctxp[((size_t)b*8 + c)*H2_ + t];
  hc[(H2_ + t)*B_ + b] = ctx;
  float p = ctx*w_gen[t] + hc[t*B_ + b]*w_gen[H2_ + t];
  if (t < E_) p += emb_table[(size_t)ids[b]*E_ + t]*w_gen[2*H2_ + t];
  float s = blk_reduce_sum(p, red);
  if (t == 0) pgen[b] = sigmoidf_(s + b_gen[0]);
}

// ---- K4: fc1, output bf16 [b][k] ----
__global__ __launch_bounds__(256) void k_fc1(const float* __restrict__ hc,
    const float* __restrict__ w_fc1, const float* __restrict__ b_fc1,
    short* __restrict__ fcb){
  __shared__ float wt[16][H4_];
  int t = threadIdx.x; int j0 = blockIdx.x*16;
  for (int idx = t; idx < 16*H4_; idx += 256) {
    int r = idx >> 9, k = idx & 511;
    wt[r][k] = w_fc1[(j0 + r)*H4_ + k];
  }
  __syncthreads();
  int jq = t >> 7, b = t & 127;
  float acc[8] = {};
  for (int k = 0; k < H4_; ++k) {
    float a = hc[k*B_ + b];
    #pragma unroll
    for (int jj = 0; jj < 8; ++jj) acc[jj] += wt[jq*8+jj][k]*a;
  }
  bf16x8 pack;
  #pragma unroll
  for (int jj = 0; jj < 8; ++jj) {
    int j = j0 + jq*8 + jj;
    pack[jj] = f2bf(tanhf(acc[jj] + b_fc1[j]));
  }
  *(bf16x8*)&fcb[(size_t)b*H4_ + j0 + jq*8] = pack;
}

// ---- K5: MFMA 32x32x16 GEMM, issue-early/write-late pipelined staging (R10
// structure, best measured). Epilogue stores bf16 logits (half the write).
__global__ __launch_bounds__(256, 2) void k_gemm2m(const short* __restrict__ fcb,
    const float* __restrict__ w_fc2, const float* __restrict__ b_fc2,
    short* __restrict__ logb){
  __shared__ __attribute__((aligned(16))) char lds[49152];
  int t = threadIdx.x;
  int w = t >> 6, l = t & 63;
  int ln = l & 31, g2 = l >> 5;
  int v0 = blockIdx.x*128;
  int v = v0 + w*32 + ln;
  int vl = w*32 + ln;

  int ar0 = t >> 2,         as0 = t & 3;
  int ar1 = (256 + t) >> 2, as1 = (256 + t) & 3;
  int aoff0 = as0*2048 + ((ar0 ^ (as0 << 1)) & 127)*16;
  int aoff1 = as1*2048 + ((ar1 ^ (as1 << 1)) & 127)*16;
  const short* ag0 = fcb + ar0*H4_ + as0*8;
  const short* ag1 = fcb + ar1*H4_ + as1*8;
  int woffs[4]; const float* wgs[4];
  #pragma unroll
  for (int p = 0; p < 4; ++p) {
    int i = p*256 + t;
    int row = i >> 3, kg = i & 7;
    woffs[p] = 8192 + kg*2048 + ((row ^ kg) & 127)*16;
    int vr = v0 + row; if (vr >= V_) vr = V_ - 1;
    wgs[p] = w_fc2 + (size_t)vr*H4_ + kg*4;
  }

  f32x16 acc0 = {}, acc1 = {}, acc2 = {}, acc3 = {};

  bf16x8 aE0, aE1; f32x4 wE0, wE1, wE2, wE3;   // even-chunk set
  bf16x8 aO0, aO1; f32x4 wO0, wO1, wO2, wO3;   // odd-chunk set

  #define LOADSET(A0, A1, W0, W1, W2, W3, c) {                                \
    A0 = *(const bf16x8*)(ag0 + (c)*32);                                      \
    A1 = *(const bf16x8*)(ag1 + (c)*32);                                      \
    W0 = *(const f32x4*)(wgs[0] + (c)*32);                                    \
    W1 = *(const f32x4*)(wgs[1] + (c)*32);                                    \
    W2 = *(const f32x4*)(wgs[2] + (c)*32);                                    \
    W3 = *(const f32x4*)(wgs[3] + (c)*32);                                    \
  }
  #define WRITESET(A0, A1, W0, W1, W2, W3, bi) {                              \
    char* bb = lds + (bi)*24576;                                              \
    *(bf16x8*)(bb + aoff0) = A0;                                              \
    *(bf16x8*)(bb + aoff1) = A1;                                              \
    *(f32x4*)(bb + woffs[0]) = W0;                                            \
    *(f32x4*)(bb + woffs[1]) = W1;                                            \
    *(f32x4*)(bb + woffs[2]) = W2;                                            \
    *(f32x4*)(bb + woffs[3]) = W3;                                            \
  }

  LOADSET(aE0, aE1, wE0, wE1, wE2, wE3, 0)
  LOADSET(aO0, aO1, wO0, wO1, wO2, wO3, 1)
  WRITESET(aE0, aE1, wE0, wE1, wE2, wE3, 0)
  LOADSET(aE0, aE1, wE0, wE1, wE2, wE3, 2)
  __syncthreads();

  for (int c = 0; c < 16; ++c) {
    if (c + 1 < 16) {
      if ((c + 1) & 1) {
        WRITESET(aO0, aO1, wO0, wO1, wO2, wO3, 1)
        if (c + 3 < 16) LOADSET(aO0, aO1, wO0, wO1, wO2, wO3, c + 3)
      } else {
        WRITESET(aE0, aE1, wE0, wE1, wE2, wE3, 0)
        if (c + 3 < 16) LOADSET(aE0, aE1, wE0, wE1, wE2, wE3, c + 3)
      }
    }
    char* Ab = lds + (c & 1)*24576;
    char* Wb = Ab + 8192;
    #pragma unroll
    for (int s = 0; s < 2; ++s) {
      int sg = s*2 + g2;
      bf16x8 a0 = *(const bf16x8*)(Ab + sg*2048 + (((0*32+ln) ^ (sg<<1)) & 127)*16);
      bf16x8 a1 = *(const bf16x8*)(Ab + sg*2048 + (((1*32+ln) ^ (sg<<1)) & 127)*16);
      bf16x8 a2 = *(const bf16x8*)(Ab + sg*2048 + (((2*32+ln) ^ (sg<<1)) & 127)*16);
      bf16x8 a3 = *(const bf16x8*)(Ab + sg*2048 + (((3*32+ln) ^ (sg<<1)) & 127)*16);
      int kgA = s*4 + g2*2;
      f32x4 f0 = *(const f32x4*)(Wb + kgA*2048 + ((vl ^ kgA) & 127)*16);
      int kgB = kgA + 1;
      f32x4 f1 = *(const f32x4*)(Wb + kgB*2048 + ((vl ^ kgB) & 127)*16);
      bf16x8 bf;
      bf[0]=f2bf(f0[0]); bf[1]=f2bf(f0[1]); bf[2]=f2bf(f0[2]); bf[3]=f2bf(f0[3]);
      bf[4]=f2bf(f1[0]); bf[5]=f2bf(f1[1]); bf[6]=f2bf(f1[2]); bf[7]=f2bf(f1[3]);
      acc0 = __builtin_amdgcn_mfma_f32_32x32x16_bf16(a0, bf, acc0, 0, 0, 0);
      acc1 = __builtin_amdgcn_mfma_f32_32x32x16_bf16(a1, bf, acc1, 0, 0, 0);
      acc2 = __builtin_amdgcn_mfma_f32_32x32x16_bf16(a2, bf, acc2, 0, 0, 0);
      acc3 = __builtin_amdgcn_mfma_f32_32x32x16_bf16(a3, bf, acc3, 0, 0, 0);
    }
    __syncthreads();
  }
  #undef LOADSET
  #undef WRITESET

  if (v < V_) {
    float bias = b_fc2[v];
    #pragma unroll
    for (int r = 0; r < 16; ++r) {
      int brow = (r & 3) + 8*(r >> 2) + 4*g2;
      logb[(size_t)(brow)*V_ + v]      = f2bf(acc0[r] + bias);
      logb[(size_t)(32 + brow)*V_ + v] = f2bf(acc1[r] + bias);
      logb[(size_t)(64 + brow)*V_ + v] = f2bf(acc2[r] + bias);
      logb[(size_t)(96 + brow)*V_ + v] = f2bf(acc3[r] + bias);
    }
  }
}

// ---- K6a: softmax partial stats over bf16 logits, grid (8, B) ----
__global__ __launch_bounds__(256) void k_smp(const unsigned short* __restrict__ logb,
    float* __restrict__ smp){
  __shared__ float rm[256], rs[256];
  int b = blockIdx.y, c = blockIdx.x, t = threadIdx.x;
  int u0 = c*3125, u1 = u0 + 3125;      // uint pairs; V/2 = 25000
  const unsigned int* lp = (const unsigned int*)(logb + (size_t)b*V_);
  float m = -1e30f, s = 0.f;
  for (int u = u0 + t; u < u1; u += 256) {
    unsigned int pr = lp[u];
    float xa = bf2f((unsigned short)(pr & 0xffff));
    float xb = bf2f((unsigned short)(pr >> 16));
    float nm = fmaxf(m, fmaxf(xa, xb));
    s = s*__expf(m - nm) + __expf(xa - nm) + __expf(xb - nm);
    m = nm;
  }
  rm[t] = m; rs[t] = s; __syncthreads();
  for (int k = 128; k > 0; k >>= 1) {
    if (t < k) {
      float m1 = rm[t], s1 = rs[t], m2 = rm[t+k], s2 = rs[t+k];
      float nm = fmaxf(m1, m2);
      rm[t] = nm; rs[t] = s1*__expf(m1-nm) + s2*__expf(m2-nm);
    }
    __syncthreads();
  }
  if (t == 0) { smp[(b*8+c)*2] = rm[0]; smp[(b*8+c)*2+1] = rs[0]; }
}

// ---- K6b: combine stats + covloss ----
__global__ __launch_bounds__(128) void k_smred_cl(const float* __restrict__ smp,
    const float* __restrict__ covp, float* __restrict__ mx,
    float* __restrict__ inv, float* __restrict__ o_cl){
  __shared__ float red[128];
  int t = threadIdx.x;
  float m = -1e30f, s = 0.f;
  #pragma unroll
  for (int c = 0; c < 8; ++c) {
    float m2 = smp[(t*8+c)*2], s2 = smp[(t*8+c)*2+1];
    float nm = fmaxf(m, m2);
    s = s*__expf(m - nm) + s2*__expf(m2 - nm);
    m = nm;
  }
  mx[t] = m; inv[t] = 1.f/s;
  red[t] = covp[t]; __syncthreads();
  for (int k = 64; k > 0; k >>= 1){ if (t < k) red[t] += red[t+k]; __syncthreads(); }
  if (t == 0) o_cl[0] = red[0];
}

// ---- K7: out = softmax(logit)*pgen (vocab part only; copy added by k_scatter) ----
__global__ __launch_bounds__(256) void k_final(const unsigned short* __restrict__ logb,
    const float* __restrict__ mx, const float* __restrict__ inv_s,
    const float* __restrict__ pgen, float* __restrict__ out){
  size_t gid = (size_t)blockIdx.x*256 + threadIdx.x;   // B*V/2 pairs
  int b = (int)(gid / (V_/2));
  int u = (int)(gid % (V_/2));
  float m = mx[b], is = inv_s[b], pg = pgen[b];
  unsigned int pr = ((const unsigned int*)(logb + (size_t)b*V_))[u];
  float2 o;
  o.x = __expf(bf2f((unsigned short)(pr & 0xffff)) - m)*is*pg;
  o.y = __expf(bf2f((unsigned short)(pr >> 16)) - m)*is*pg;
  *(float2*)&out[(size_t)b*V_ + u*2] = o;
}

// ---- K8: scatter copy-dist contribution into out ----
__global__ __launch_bounds__(256) void k_scatter(const int* __restrict__ src,
    const float* __restrict__ attn, const float* __restrict__ pgen,
    float* __restrict__ out){
  int b = blockIdx.x, t = threadIdx.x;
  float c1 = 1.f - pgen[b];
  for (int tt = t; tt < T_; tt += 256)
    atomicAdd(&out[(size_t)b*V_ + src[b*T_ + tt]], attn[b*T_ + tt]*c1);
}

extern "C" void kernel_launch(void* const* d_in, const int* in_sizes, int n_in,
                              void* d_out, int out_size, void* d_ws, size_t ws_size,
                              hipStream_t stream) {
  const int*   ids       = (const int*)  d_in[0];
  const float* pre_h     = (const float*)d_in[1];
  const float* pre_c     = (const float*)d_in[2];
  const float* enc       = (const float*)d_in[3];
  const int*   src       = (const int*)  d_in[4];
  const float* cov       = (const float*)d_in[5];
  const float* emb_table = (const float*)d_in[6];
  const float* w_ih      = (const float*)d_in[7];
  const float* w_hh      = (const float*)d_in[8];
  const float* b_ih      = (const float*)d_in[9];
  const float* b_hh      = (const float*)d_in[10];
  const float* w_align   = (const float*)d_in[11];
  const float* b_align   = (const float*)d_in[12];
  const float* w_cov     = (const float*)d_in[13];
  const float* b_cov     = (const float*)d_in[14];
  const float* w_fc1     = (const float*)d_in[15];
  const float* b_fc1     = (const float*)d_in[16];
  const float* w_fc2     = (const float*)d_in[17];
  const float* b_fc2     = (const float*)d_in[18];
  const float* w_gen     = (const float*)d_in[19];
  const float* b_gen     = (const float*)d_in[20];

  float* out = (float*)d_out;
  float* ws  = (float*)d_ws;

  float* o_out    = out;
  float* o_h      = out + OFF_H;
  float* o_c      = out + OFF_C;
  float* o_attn   = out + OFF_ATTN;
  float* o_copy   = out + OFF_COPY;
  float* o_newcov = out + OFF_NEWCOV;
  float* o_cl     = out + OFF_COVLOSS;
  short* logb     = (short*)(ws + WS_LOGB);

  k_zero <<<(B_*V_/4 + 255)/256, 256, 0, stream>>>(o_copy);
  k_act  <<<192, 256, 0, stream>>>(ids, pre_h, emb_table, w_align, w_cov, b_cov,
                                   ws + WS_ACT, ws + WS_AB);
  k_gates<<<128, 256, 0, stream>>>(ws + WS_ACT, w_ih, w_hh, b_ih, b_hh, ws + WS_GATES);
  k_lstm <<<128, 256, 0, stream>>>(ws + WS_GATES, pre_c, w_align, o_h, o_c,
                                   ws + WS_HC, ws + WS_HDOT);
  k_scores<<<dim3(8,128), 256, 0, stream>>>(enc, cov, w_align, b_align,
                                   ws + WS_HDOT, ws + WS_AB, ws + WS_SC);
  k_soft <<<128, 256, 0, stream>>>(ws + WS_SC, cov, src, o_attn, o_newcov, o_copy,
                                   ws + WS_COVP, ws + WS_ATTN);
  k_ctx  <<<dim3(8,128), 256, 0, stream>>>(enc, ws + WS_ATTN, ws + WS_CTXP);
  k_ctxpgen<<<128, 256, 0, stream>>>(ws + WS_CTXP, ids, emb_table, w_gen, b_gen,
                                   ws + WS_HC, ws + WS_PGEN);
  k_fc1  <<<32, 256, 0, stream>>>(ws + WS_HC, w_fc1, b_fc1, (short*)(ws + WS_FCB));
  k_gemm2m<<<(V_ + 127)/128, 256, 0, stream>>>((const short*)(ws + WS_FCB),
                                   w_fc2, b_fc2, logb);
  k_smp  <<<dim3(8,128), 256, 0, stream>>>((const unsigned short*)logb, ws + WS_SMP);
  k_smred_cl<<<1, 128, 0, stream>>>(ws + WS_SMP, ws + WS_COVP,
                                   ws + WS_MAX, ws + WS_INV, o_cl);
  k_final<<<(int)(((size_t)B_*V_/2)/256), 256, 0, stream>>>(
      (const unsigned short*)logb, ws + WS_MAX, ws + WS_INV, ws + WS_PGEN, o_out);
  k_scatter<<<128, 256, 0, stream>>>(src, o_attn, ws + WS_PGEN, o_out);
}

// Round 15
// 142.744 us; speedup vs baseline: 1.1225x; 1.0039x over previous
//
#include <hip/hip_runtime.h>
#include <hip/hip_bf16.h>
#include <math.h>

#define B_  128
#define T_  400
#define E_  128
#define H2_ 256
#define H4_ 512
#define V_  50000
#define G4_ 1024   // 4*H2
#define KACT 384   // E + H2

// output offsets (floats)
#define OFF_H       6400000
#define OFF_C       6432768
#define OFF_ATTN    6465536
#define OFF_COPY    6516736
#define OFF_NEWCOV 12916736
#define OFF_COVLOSS 12967936

// workspace offsets (floats)
#define WS_ACT   0                      // [384][128] act (emb;h0) [k][b]
#define WS_GATES (WS_ACT + KACT*B_)     // [1024][128] gates [j][b]
#define WS_HC    (WS_GATES + G4_*B_)    // [512][128]  (h;ctx) [k][b]
#define WS_FCB   (WS_HC + H4_*B_)       // [128][512]  fc bf16 [b][k]
#define WS_SC    (WS_FCB + H4_*B_/2)    // [128][400]  scores
#define WS_ATTN  (WS_SC + B_*T_)        // [128][400]  attn
#define WS_CTXP  (WS_ATTN + B_*T_)      // [128][8][256] context partials
#define WS_SMP   (WS_CTXP + B_*8*H2_)   // [128][8][2] softmax partials
#define WS_HDOT  (WS_SMP + B_*8*2)      // [128]
#define WS_COVP  (WS_HDOT + B_)         // [128]
#define WS_PGEN  (WS_COVP + B_)         // [128]
#define WS_MAX   (WS_PGEN + B_)         // [128]
#define WS_INV   (WS_MAX + B_)          // [128]
#define WS_AB    (WS_INV + B_)          // [2] alpha, beta (+pad)
#define WS_LOGB  (WS_AB + 16)           // [128][50000] bf16 logits (as shorts)

typedef __attribute__((ext_vector_type(8))) short bf16x8;
typedef __attribute__((ext_vector_type(4))) float f32x4;
typedef __attribute__((ext_vector_type(16))) float f32x16;

__device__ inline float sigmoidf_(float x){ return 1.f/(1.f+__expf(-x)); }

__device__ inline short f2bf(float x){
  __hip_bfloat16 h = __float2bfloat16(x);
  return *reinterpret_cast<short*>(&h);
}
__device__ inline float bf2f(unsigned short u){
  unsigned int x = ((unsigned int)u) << 16;
  return *reinterpret_cast<float*>(&x);
}

__device__ inline float blk_reduce_sum(float v, float* red){
  int t = threadIdx.x;
  red[t] = v; __syncthreads();
  for (int s = 128; s > 0; s >>= 1){ if (t < s) red[t] += red[t+s]; __syncthreads(); }
  float r = red[0]; __syncthreads(); return r;
}
__device__ inline float blk_reduce_max(float v, float* red){
  int t = threadIdx.x;
  red[t] = v; __syncthreads();
  for (int s = 128; s > 0; s >>= 1){ if (t < s) red[t] = fmaxf(red[t], red[t+s]); __syncthreads(); }
  float r = red[0]; __syncthreads(); return r;
}

// ---- K_zero: fast zero of o_copy ----
__global__ __launch_bounds__(256) void k_zero(float* __restrict__ p){
  size_t i = ((size_t)blockIdx.x*256 + threadIdx.x)*4;
  if (i < (size_t)B_*V_)
    *(float4*)&p[i] = make_float4(0.f,0.f,0.f,0.f);
}

// ---- K0: act[k][b] = concat(emb,h0) transposed; block 0 also computes alpha/beta ----
__global__ __launch_bounds__(256) void k_act(const int* __restrict__ ids,
    const float* __restrict__ pre_h, const float* __restrict__ emb_table,
    const float* __restrict__ w_align, const float* __restrict__ w_cov,
    const float* __restrict__ b_cov, float* __restrict__ act,
    float* __restrict__ ab){
  __shared__ float red[256];
  int t = threadIdx.x;
  int idx = blockIdx.x*256 + t;
  int k = idx >> 7, b = idx & 127;
  float v = (k < E_) ? emb_table[(size_t)ids[b]*E_ + k]
                     : pre_h[b*H2_ + (k - E_)];
  act[idx] = v;
  if (blockIdx.x == 0) {
    float wa = w_align[2*H2_ + t];
    float alpha = blk_reduce_sum(w_cov[t]*wa, red);
    float beta  = blk_reduce_sum(b_cov[t]*wa, red);
    if (t == 0) { ab[0] = alpha; ab[1] = beta; }
  }
}

// ---- K1: gates[j][b] ----
__global__ __launch_bounds__(256) void k_gates(const float* __restrict__ act,
    const float* __restrict__ w_ih, const float* __restrict__ w_hh,
    const float* __restrict__ b_ih, const float* __restrict__ b_hh,
    float* __restrict__ gates){
  __shared__ float wt[8][KACT];
  int t = threadIdx.x; int j0 = blockIdx.x*8;
  for (int idx = t; idx < 8*KACT; idx += 256) {
    int r = idx / KACT, k = idx % KACT;
    int j = j0 + r;
    wt[r][k] = (k < E_) ? w_ih[j*E_ + k] : w_hh[j*H2_ + (k - E_)];
  }
  __syncthreads();
  int jq = t >> 7, b = t & 127;
  float acc[4] = {0.f,0.f,0.f,0.f};
  for (int k = 0; k < KACT; ++k) {
    float a = act[k*B_ + b];
    #pragma unroll
    for (int jj = 0; jj < 4; ++jj) acc[jj] += wt[jq*4+jj][k]*a;
  }
  #pragma unroll
  for (int jj = 0; jj < 4; ++jj) {
    int j = j0 + jq*4 + jj;
    gates[j*B_ + b] = acc[jj] + b_ih[j] + b_hh[j];
  }
}

// ---- K2: LSTM elementwise + hdot ----
__global__ __launch_bounds__(256) void k_lstm(const float* __restrict__ gates,
    const float* __restrict__ pre_c, const float* __restrict__ w_align,
    float* __restrict__ o_h, float* __restrict__ o_c,
    float* __restrict__ hc, float* __restrict__ hdot){
  __shared__ float red[256];
  int b = blockIdx.x, k = threadIdx.x;
  float i_ = gates[(0*H2_ + k)*B_ + b];
  float f_ = gates[(1*H2_ + k)*B_ + b];
  float g_ = gates[(2*H2_ + k)*B_ + b];
  float o_ = gates[(3*H2_ + k)*B_ + b];
  float c = sigmoidf_(f_)*pre_c[b*H2_ + k] + sigmoidf_(i_)*tanhf(g_);
  float h = sigmoidf_(o_)*tanhf(c);
  o_h[b*H2_ + k] = h;
  o_c[b*H2_ + k] = c;
  hc[k*B_ + b] = h;
  float s = blk_reduce_sum(h * w_align[H2_ + k], red);
  if (k == 0) hdot[b] = s;
}

// ---- K3a: scores, grid (8 chunks of 50, B) ----
__global__ __launch_bounds__(256) void k_scores(const float* __restrict__ enc,
    const float* __restrict__ cov, const float* __restrict__ w_align,
    const float* __restrict__ b_align, const float* __restrict__ hdot,
    const float* __restrict__ ab, float* __restrict__ sc){
  int b = blockIdx.y, c = blockIdx.x;
  int t = threadIdx.x, wave = t >> 6, lane = t & 63;
  float4 wa4 = *(const float4*)&w_align[lane*4];
  float hd = hdot[b], alpha = ab[0], beta = ab[1], ba = b_align[0];
  int t0 = c*50;
  for (int tt = t0 + wave; tt < t0 + 50; tt += 4) {
    const float4* ep = (const float4*)&enc[((size_t)b*T_ + tt)*H2_];
    float4 e4 = ep[lane];
    float d = e4.x*wa4.x + e4.y*wa4.y + e4.z*wa4.z + e4.w*wa4.w;
    #pragma unroll
    for (int m = 32; m >= 1; m >>= 1) d += __shfl_xor(d, m);
    if (lane == 0)
      sc[b*T_ + tt] = tanhf(d + hd + alpha*cov[b*T_ + tt] + beta + ba);
  }
}

// ---- K3b: softmax over T + scatter + newcov + covloss partial ----
__global__ __launch_bounds__(256) void k_soft(const float* __restrict__ sc_in,
    const float* __restrict__ cov, const int* __restrict__ src,
    float* __restrict__ o_attn, float* __restrict__ o_newcov,
    float* __restrict__ o_copy, float* __restrict__ covp,
    float* __restrict__ attn_ws){
  __shared__ float red[256];
  int b = blockIdx.x, t = threadIdx.x;
  float x1 = sc_in[b*T_ + t];
  float x2 = (t + 256 < T_) ? sc_in[b*T_ + t + 256] : -1e30f;
  float mx = blk_reduce_max(fmaxf(x1, x2), red);
  float e1 = __expf(x1 - mx);
  float e2 = (t + 256 < T_) ? __expf(x2 - mx) : 0.f;
  float sum = blk_reduce_sum(e1 + e2, red);
  float inv = 1.f/sum;
  float cl;
  {
    float a1 = e1*inv; float c1 = cov[b*T_ + t];
    attn_ws[b*T_ + t] = a1;
    o_attn[b*T_ + t] = a1;
    o_newcov[b*T_ + t] = c1 + a1;
    atomicAdd(&o_copy[(size_t)b*V_ + src[b*T_ + t]], a1);
    cl = fminf(a1, c1);
  }
  if (t + 256 < T_) {
    float a2 = e2*inv; float c2 = cov[b*T_ + t + 256];
    attn_ws[b*T_ + t + 256] = a2;
    o_attn[b*T_ + t + 256] = a2;
    o_newcov[b*T_ + t + 256] = c2 + a2;
    atomicAdd(&o_copy[(size_t)b*V_ + src[b*T_ + t + 256]], a2);
    cl += fminf(a2, c2);
  }
  float clsum = blk_reduce_sum(cl, red);
  if (t == 0) covp[b] = clsum;
}

// ---- K3c: context partials, grid (8 chunks, B) ----
__global__ __launch_bounds__(256) void k_ctx(const float* __restrict__ enc,
    const float* __restrict__ attn_ws, float* __restrict__ ctxp){
  __shared__ float a_s[50];
  int b = blockIdx.y, c = blockIdx.x, e = threadIdx.x;
  int t0 = c*50;
  if (e < 50) a_s[e] = attn_ws[b*T_ + t0 + e];
  __syncthreads();
  float acc = 0.f;
  #pragma unroll 5
  for (int i = 0; i < 50; ++i)
    acc += a_s[i] * enc[((size_t)b*T_ + t0 + i)*H2_ + e];
  ctxp[((size_t)b*8 + c)*H2_ + e] = acc;
}

// ---- K3d: context reduce + pgen ----
__global__ __launch_bounds__(256) void k_ctxpgen(const float* __restrict__ ctxp,
    const int* __restrict__ ids, const float* __restrict__ emb_table,
    const float* __restrict__ w_gen, const float* __restrict__ b_gen,
    float* __restrict__ hc, float* __restrict__ pgen){
  __shared__ float red[256];
  int b = blockIdx.x, t = threadIdx.x;
  float ctx = 0.f;
  #pragma unroll
  for (int c = 0; c < 8; ++c) ctx += ctxp[((size_t)b*8 + c)*H2_ + t];
  hc[(H2_ + t)*B_ + b] = ctx;
  float p = ctx*w_gen[t] + hc[t*B_ + b]*w_gen[H2_ + t];
  if (t < E_) p += emb_table[(size_t)ids[b]*E_ + t]*w_gen[2*H2_ + t];
  float s = blk_reduce_sum(p, red);
  if (t == 0) pgen[b] = sigmoidf_(s + b_gen[0]);
}

// ---- K4: fc1, output bf16 [b][k] ----
__global__ __launch_bounds__(256) void k_fc1(const float* __restrict__ hc,
    const float* __restrict__ w_fc1, const float* __restrict__ b_fc1,
    short* __restrict__ fcb){
  __shared__ float wt[16][H4_];
  int t = threadIdx.x; int j0 = blockIdx.x*16;
  for (int idx = t; idx < 16*H4_; idx += 256) {
    int r = idx >> 9, k = idx & 511;
    wt[r][k] = w_fc1[(j0 + r)*H4_ + k];
  }
  __syncthreads();
  int jq = t >> 7, b = t & 127;
  float acc[8] = {};
  for (int k = 0; k < H4_; ++k) {
    float a = hc[k*B_ + b];
    #pragma unroll
    for (int jj = 0; jj < 8; ++jj) acc[jj] += wt[jq*8+jj][k]*a;
  }
  bf16x8 pack;
  #pragma unroll
  for (int jj = 0; jj < 8; ++jj) {
    int j = j0 + jq*8 + jj;
    pack[jj] = f2bf(tanhf(acc[jj] + b_fc1[j]));
  }
  *(bf16x8*)&fcb[(size_t)b*H4_ + j0 + jq*8] = pack;
}

// ---- K5: MFMA 32x32x16 GEMM, issue-early/write-late pipelined staging (R10
// structure). bf16 logits epilogue. Single change vs R14: 3 blocks/CU
// (launch_bounds(256,3); LDS 48KB x3 = 144KB <= 160KB) so co-resident blocks
// overlap each other's per-iteration vmcnt drains.
__global__ __launch_bounds__(256, 3) void k_gemm2m(const short* __restrict__ fcb,
    const float* __restrict__ w_fc2, const float* __restrict__ b_fc2,
    short* __restrict__ logb){
  __shared__ __attribute__((aligned(16))) char lds[49152];
  int t = threadIdx.x;
  int w = t >> 6, l = t & 63;
  int ln = l & 31, g2 = l >> 5;
  int v0 = blockIdx.x*128;
  int v = v0 + w*32 + ln;
  int vl = w*32 + ln;

  int ar0 = t >> 2,         as0 = t & 3;
  int ar1 = (256 + t) >> 2, as1 = (256 + t) & 3;
  int aoff0 = as0*2048 + ((ar0 ^ (as0 << 1)) & 127)*16;
  int aoff1 = as1*2048 + ((ar1 ^ (as1 << 1)) & 127)*16;
  const short* ag0 = fcb + ar0*H4_ + as0*8;
  const short* ag1 = fcb + ar1*H4_ + as1*8;
  int woffs[4]; const float* wgs[4];
  #pragma unroll
  for (int p = 0; p < 4; ++p) {
    int i = p*256 + t;
    int row = i >> 3, kg = i & 7;
    woffs[p] = 8192 + kg*2048 + ((row ^ kg) & 127)*16;
    int vr = v0 + row; if (vr >= V_) vr = V_ - 1;
    wgs[p] = w_fc2 + (size_t)vr*H4_ + kg*4;
  }

  f32x16 acc0 = {}, acc1 = {}, acc2 = {}, acc3 = {};

  bf16x8 aE0, aE1; f32x4 wE0, wE1, wE2, wE3;   // even-chunk set
  bf16x8 aO0, aO1; f32x4 wO0, wO1, wO2, wO3;   // odd-chunk set

  #define LOADSET(A0, A1, W0, W1, W2, W3, c) {                                \
    A0 = *(const bf16x8*)(ag0 + (c)*32);                                      \
    A1 = *(const bf16x8*)(ag1 + (c)*32);                                      \
    W0 = *(const f32x4*)(wgs[0] + (c)*32);                                    \
    W1 = *(const f32x4*)(wgs[1] + (c)*32);                                    \
    W2 = *(const f32x4*)(wgs[2] + (c)*32);                                    \
    W3 = *(const f32x4*)(wgs[3] + (c)*32);                                    \
  }
  #define WRITESET(A0, A1, W0, W1, W2, W3, bi) {                              \
    char* bb = lds + (bi)*24576;                                              \
    *(bf16x8*)(bb + aoff0) = A0;                                              \
    *(bf16x8*)(bb + aoff1) = A1;                                              \
    *(f32x4*)(bb + woffs[0]) = W0;                                            \
    *(f32x4*)(bb + woffs[1]) = W1;                                            \
    *(f32x4*)(bb + woffs[2]) = W2;                                            \
    *(f32x4*)(bb + woffs[3]) = W3;                                            \
  }

  LOADSET(aE0, aE1, wE0, wE1, wE2, wE3, 0)
  LOADSET(aO0, aO1, wO0, wO1, wO2, wO3, 1)
  WRITESET(aE0, aE1, wE0, wE1, wE2, wE3, 0)
  LOADSET(aE0, aE1, wE0, wE1, wE2, wE3, 2)
  __syncthreads();

  for (int c = 0; c < 16; ++c) {
    if (c + 1 < 16) {
      if ((c + 1) & 1) {
        WRITESET(aO0, aO1, wO0, wO1, wO2, wO3, 1)
        if (c + 3 < 16) LOADSET(aO0, aO1, wO0, wO1, wO2, wO3, c + 3)
      } else {
        WRITESET(aE0, aE1, wE0, wE1, wE2, wE3, 0)
        if (c + 3 < 16) LOADSET(aE0, aE1, wE0, wE1, wE2, wE3, c + 3)
      }
    }
    char* Ab = lds + (c & 1)*24576;
    char* Wb = Ab + 8192;
    #pragma unroll
    for (int s = 0; s < 2; ++s) {
      int sg = s*2 + g2;
      bf16x8 a0 = *(const bf16x8*)(Ab + sg*2048 + (((0*32+ln) ^ (sg<<1)) & 127)*16);
      bf16x8 a1 = *(const bf16x8*)(Ab + sg*2048 + (((1*32+ln) ^ (sg<<1)) & 127)*16);
      bf16x8 a2 = *(const bf16x8*)(Ab + sg*2048 + (((2*32+ln) ^ (sg<<1)) & 127)*16);
      bf16x8 a3 = *(const bf16x8*)(Ab + sg*2048 + (((3*32+ln) ^ (sg<<1)) & 127)*16);
      int kgA = s*4 + g2*2;
      f32x4 f0 = *(const f32x4*)(Wb + kgA*2048 + ((vl ^ kgA) & 127)*16);
      int kgB = kgA + 1;
      f32x4 f1 = *(const f32x4*)(Wb + kgB*2048 + ((vl ^ kgB) & 127)*16);
      bf16x8 bf;
      bf[0]=f2bf(f0[0]); bf[1]=f2bf(f0[1]); bf[2]=f2bf(f0[2]); bf[3]=f2bf(f0[3]);
      bf[4]=f2bf(f1[0]); bf[5]=f2bf(f1[1]); bf[6]=f2bf(f1[2]); bf[7]=f2bf(f1[3]);
      acc0 = __builtin_amdgcn_mfma_f32_32x32x16_bf16(a0, bf, acc0, 0, 0, 0);
      acc1 = __builtin_amdgcn_mfma_f32_32x32x16_bf16(a1, bf, acc1, 0, 0, 0);
      acc2 = __builtin_amdgcn_mfma_f32_32x32x16_bf16(a2, bf, acc2, 0, 0, 0);
      acc3 = __builtin_amdgcn_mfma_f32_32x32x16_bf16(a3, bf, acc3, 0, 0, 0);
    }
    __syncthreads();
  }
  #undef LOADSET
  #undef WRITESET

  if (v < V_) {
    float bias = b_fc2[v];
    #pragma unroll
    for (int r = 0; r < 16; ++r) {
      int brow = (r & 3) + 8*(r >> 2) + 4*g2;
      logb[(size_t)(brow)*V_ + v]      = f2bf(acc0[r] + bias);
      logb[(size_t)(32 + brow)*V_ + v] = f2bf(acc1[r] + bias);
      logb[(size_t)(64 + brow)*V_ + v] = f2bf(acc2[r] + bias);
      logb[(size_t)(96 + brow)*V_ + v] = f2bf(acc3[r] + bias);
    }
  }
}

// ---- K6a: softmax partial stats over bf16 logits, grid (8, B) ----
__global__ __launch_bounds__(256) void k_smp(const unsigned short* __restrict__ logb,
    float* __restrict__ smp){
  __shared__ float rm[256], rs[256];
  int b = blockIdx.y, c = blockIdx.x, t = threadIdx.x;
  int u0 = c*3125, u1 = u0 + 3125;      // uint pairs; V/2 = 25000
  const unsigned int* lp = (const unsigned int*)(logb + (size_t)b*V_);
  float m = -1e30f, s = 0.f;
  for (int u = u0 + t; u < u1; u += 256) {
    unsigned int pr = lp[u];
    float xa = bf2f((unsigned short)(pr & 0xffff));
    float xb = bf2f((unsigned short)(pr >> 16));
    float nm = fmaxf(m, fmaxf(xa, xb));
    s = s*__expf(m - nm) + __expf(xa - nm) + __expf(xb - nm);
    m = nm;
  }
  rm[t] = m; rs[t] = s; __syncthreads();
  for (int k = 128; k > 0; k >>= 1) {
    if (t < k) {
      float m1 = rm[t], s1 = rs[t], m2 = rm[t+k], s2 = rs[t+k];
      float nm = fmaxf(m1, m2);
      rm[t] = nm; rs[t] = s1*__expf(m1-nm) + s2*__expf(m2-nm);
    }
    __syncthreads();
  }
  if (t == 0) { smp[(b*8+c)*2] = rm[0]; smp[(b*8+c)*2+1] = rs[0]; }
}

// ---- K6b: combine stats + covloss ----
__global__ __launch_bounds__(128) void k_smred_cl(const float* __restrict__ smp,
    const float* __restrict__ covp, float* __restrict__ mx,
    float* __restrict__ inv, float* __restrict__ o_cl){
  __shared__ float red[128];
  int t = threadIdx.x;
  float m = -1e30f, s = 0.f;
  #pragma unroll
  for (int c = 0; c < 8; ++c) {
    float m2 = smp[(t*8+c)*2], s2 = smp[(t*8+c)*2+1];
    float nm = fmaxf(m, m2);
    s = s*__expf(m - nm) + s2*__expf(m2 - nm);
    m = nm;
  }
  mx[t] = m; inv[t] = 1.f/s;
  red[t] = covp[t]; __syncthreads();
  for (int k = 64; k > 0; k >>= 1){ if (t < k) red[t] += red[t+k]; __syncthreads(); }
  if (t == 0) o_cl[0] = red[0];
}

// ---- K7: out = softmax(logit)*pgen (vocab part only; copy added by k_scatter) ----
__global__ __launch_bounds__(256) void k_final(const unsigned short* __restrict__ logb,
    const float* __restrict__ mx, const float* __restrict__ inv_s,
    const float* __restrict__ pgen, float* __restrict__ out){
  size_t gid = (size_t)blockIdx.x*256 + threadIdx.x;   // B*V/2 pairs
  int b = (int)(gid / (V_/2));
  int u = (int)(gid % (V_/2));
  float m = mx[b], is = inv_s[b], pg = pgen[b];
  unsigned int pr = ((const unsigned int*)(logb + (size_t)b*V_))[u];
  float2 o;
  o.x = __expf(bf2f((unsigned short)(pr & 0xffff)) - m)*is*pg;
  o.y = __expf(bf2f((unsigned short)(pr >> 16)) - m)*is*pg;
  *(float2*)&out[(size_t)b*V_ + u*2] = o;
}

// ---- K8: scatter copy-dist contribution into out ----
__global__ __launch_bounds__(256) void k_scatter(const int* __restrict__ src,
    const float* __restrict__ attn, const float* __restrict__ pgen,
    float* __restrict__ out){
  int b = blockIdx.x, t = threadIdx.x;
  float c1 = 1.f - pgen[b];
  for (int tt = t; tt < T_; tt += 256)
    atomicAdd(&out[(size_t)b*V_ + src[b*T_ + tt]], attn[b*T_ + tt]*c1);
}

extern "C" void kernel_launch(void* const* d_in, const int* in_sizes, int n_in,
                              void* d_out, int out_size, void* d_ws, size_t ws_size,
                              hipStream_t stream) {
  const int*   ids       = (const int*)  d_in[0];
  const float* pre_h     = (const float*)d_in[1];
  const float* pre_c     = (const float*)d_in[2];
  const float* enc       = (const float*)d_in[3];
  const int*   src       = (const int*)  d_in[4];
  const float* cov       = (const float*)d_in[5];
  const float* emb_table = (const float*)d_in[6];
  const float* w_ih      = (const float*)d_in[7];
  const float* w_hh      = (const float*)d_in[8];
  const float* b_ih      = (const float*)d_in[9];
  const float* b_hh      = (const float*)d_in[10];
  const float* w_align   = (const float*)d_in[11];
  const float* b_align   = (const float*)d_in[12];
  const float* w_cov     = (const float*)d_in[13];
  const float* b_cov     = (const float*)d_in[14];
  const float* w_fc1     = (const float*)d_in[15];
  const float* b_fc1     = (const float*)d_in[16];
  const float* w_fc2     = (const float*)d_in[17];
  const float* b_fc2     = (const float*)d_in[18];
  const float* w_gen     = (const float*)d_in[19];
  const float* b_gen     = (const float*)d_in[20];

  float* out = (float*)d_out;
  float* ws  = (float*)d_ws;

  float* o_out    = out;
  float* o_h      = out + OFF_H;
  float* o_c      = out + OFF_C;
  float* o_attn   = out + OFF_ATTN;
  float* o_copy   = out + OFF_COPY;
  float* o_newcov = out + OFF_NEWCOV;
  float* o_cl     = out + OFF_COVLOSS;
  short* logb     = (short*)(ws + WS_LOGB);

  k_zero <<<(B_*V_/4 + 255)/256, 256, 0, stream>>>(o_copy);
  k_act  <<<192, 256, 0, stream>>>(ids, pre_h, emb_table, w_align, w_cov, b_cov,
                                   ws + WS_ACT, ws + WS_AB);
  k_gates<<<128, 256, 0, stream>>>(ws + WS_ACT, w_ih, w_hh, b_ih, b_hh, ws + WS_GATES);
  k_lstm <<<128, 256, 0, stream>>>(ws + WS_GATES, pre_c, w_align, o_h, o_c,
                                   ws + WS_HC, ws + WS_HDOT);
  k_scores<<<dim3(8,128), 256, 0, stream>>>(enc, cov, w_align, b_align,
                                   ws + WS_HDOT, ws + WS_AB, ws + WS_SC);
  k_soft <<<128, 256, 0, stream>>>(ws + WS_SC, cov, src, o_attn, o_newcov, o_copy,
                                   ws + WS_COVP, ws + WS_ATTN);
  k_ctx  <<<dim3(8,128), 256, 0, stream>>>(enc, ws + WS_ATTN, ws + WS_CTXP);
  k_ctxpgen<<<128, 256, 0, stream>>>(ws + WS_CTXP, ids, emb_table, w_gen, b_gen,
                                   ws + WS_HC, ws + WS_PGEN);
  k_fc1  <<<32, 256, 0, stream>>>(ws + WS_HC, w_fc1, b_fc1, (short*)(ws + WS_FCB));
  k_gemm2m<<<(V_ + 127)/128, 256, 0, stream>>>((const short*)(ws + WS_FCB),
                                   w_fc2, b_fc2, logb);
  k_smp  <<<dim3(8,128), 256, 0, stream>>>((const unsigned short*)logb, ws + WS_SMP);
  k_smred_cl<<<1, 128, 0, stream>>>(ws + WS_SMP, ws + WS_COVP,
                                   ws + WS_MAX, ws + WS_INV, o_cl);
  k_final<<<(int)(((size_t)B_*V_/2)/256), 256, 0, stream>>>(
      (const unsigned short*)logb, ws + WS_MAX, ws + WS_INV, ws + WS_PGEN, o_out);
  k_scatter<<<128, 256, 0, stream>>>(src, o_attn, ws + WS_PGEN, o_out);
}